// Round 1
// baseline (267.549 us; speedup 1.0000x reference)
//
#include <hip/hip_runtime.h>

// ---------------------------------------------------------------------------
// Compile-time tables: Gauss-Legendre(12) nodes/weights, normalized assoc.
// Legendre at the nodes, sqrt(2)*cos/sin(m*alpha) tables. All constexpr so
// the unrolled device loops fold them into instruction literals.
// ---------------------------------------------------------------------------
namespace tabs {

constexpr double PI_ = 3.14159265358979323846;

constexpr double csqrt(double x) {
  double g = x > 1.0 ? x : 1.0;
  for (int i = 0; i < 48; ++i) g = 0.5 * (g + x / g);
  return g;
}
constexpr double ccos(double x) {  // |x| <= pi
  double x2 = x * x, t = 1.0, s = 1.0;
  for (int k = 1; k <= 20; ++k) { t *= -x2 / ((2.0 * k - 1.0) * (2.0 * k)); s += t; }
  return s;
}
constexpr double csin(double x) {  // |x| <= pi
  double x2 = x * x, t = x, s = x;
  for (int k = 1; k <= 20; ++k) { t *= -x2 / ((2.0 * k) * (2.0 * k + 1.0)); s += t; }
  return s;
}

struct GL { double x[12]; double w[12]; };

constexpr GL gl12() {
  GL g{};
  for (int i = 0; i < 12; ++i) {
    double x = ccos(PI_ * (i + 0.75) / 12.5);
    for (int it = 0; it < 50; ++it) {
      double p0 = 1.0, p1 = x;
      for (int k = 2; k <= 12; ++k) { double pk = ((2.0 * k - 1.0) * x * p1 - (k - 1.0) * p0) / k; p0 = p1; p1 = pk; }
      double dp = 12.0 * (x * p1 - p0) / (x * x - 1.0);
      x -= p1 / dp;
    }
    double p0 = 1.0, p1 = x;
    for (int k = 2; k <= 12; ++k) { double pk = ((2.0 * k - 1.0) * x * p1 - (k - 1.0) * p0) / k; p0 = p1; p1 = pk; }
    double dp = 12.0 * (x * p1 - p0) / (x * x - 1.0);
    g.x[i] = x;
    g.w[i] = 2.0 / ((1.0 - x * x) * dp * dp);
  }
  return g;
}

struct Tables {
  float PA[12][36];  // Pbar_l^{|m|}(x_b) indexed by SH index k
  float PB[12][36];  // PA * wq[b] * (2*pi/12)
  float CT[12][6];   // m=0: 1 ; m>0: sqrt(2)*cos(m*alpha_a)
  float ST[12][6];   // m>0: sqrt(2)*sin(m*alpha_a)
  int   M5[36];      // m+5 for SH index k
  int   LK[36];      // l for SH index k
};

constexpr Tables make() {
  Tables t{};
  GL g = gl12();
  for (int b = 0; b < 12; ++b) {
    double x = g.x[b];
    double s = csqrt(1.0 - x * x);
    double P[6][6] = {};
    P[0][0] = csqrt(1.0 / (4.0 * PI_));
    for (int m = 1; m <= 5; ++m) P[m][m] = csqrt((2.0 * m + 1.0) / (2.0 * m)) * s * P[m - 1][m - 1];
    for (int m = 0; m < 5; ++m)  P[m + 1][m] = csqrt(2.0 * m + 3.0) * x * P[m][m];
    for (int m = 0; m <= 5; ++m)
      for (int l = m + 2; l <= 5; ++l) {
        double aa = csqrt((4.0 * l * l - 1.0) / (double)(l * l - m * m));
        double bb = csqrt(((l - 1.0) * (l - 1.0) - (double)(m * m)) / (4.0 * (l - 1.0) * (l - 1.0) - 1.0));
        P[l][m] = aa * (x * P[l - 1][m] - bb * P[l - 2][m]);
      }
    for (int l = 0; l <= 5; ++l)
      for (int m = -l; m <= l; ++m) {
        int k = l * l + l + m, am = m < 0 ? -m : m;
        t.PA[b][k] = (float)P[l][am];
        t.PB[b][k] = (float)(P[l][am] * g.w[b] * (2.0 * PI_ / 12.0));
      }
  }
  double r2 = csqrt(2.0);
  for (int a = 0; a < 12; ++a) {
    t.CT[a][0] = 1.0f; t.ST[a][0] = 0.0f;
    for (int m = 1; m <= 5; ++m) {
      int q = (m * a) % 12;               // angle = 2*pi*q/12, exact reduction
      double ang = 2.0 * PI_ * q / 12.0;
      if (ang > PI_) ang -= 2.0 * PI_;
      t.CT[a][m] = (float)(r2 * ccos(ang));
      t.ST[a][m] = (float)(r2 * csin(ang));
    }
  }
  for (int l = 0; l <= 5; ++l)
    for (int m = -l; m <= l; ++m) { int k = l * l + l + m; t.M5[k] = m + 5; t.LK[k] = l; }
  return t;
}

}  // namespace tabs

__device__ constexpr tabs::Tables T = tabs::make();

__device__ __forceinline__ unsigned bf16rn(float x) {
  unsigned u = __float_as_uint(x);
  return (u + 0x7FFFu + ((u >> 16) & 1u)) >> 16;
}

// One thread = one (atom, channel) row. Block 128 = one atom.
__global__ __launch_bounds__(128, 2)
void gaunt_s2_kernel(const float* __restrict__ feat,
                     const float* __restrict__ atype,
                     const float* __restrict__ wts,
                     float* __restrict__ out) {
  __shared__ unsigned fsh[72][128];  // f[b][a] bf16-packed pairs, per thread

  const int tid = threadIdx.x;
  const int atom = blockIdx.x;
  const size_t row = (size_t)atom * 128 + tid;

  float c0[36];
  {
    const float4* p = reinterpret_cast<const float4*>(feat + row * 36);
#pragma unroll
    for (int i = 0; i < 9; ++i) {
      float4 v = p[i];
      c0[4 * i + 0] = v.x; c0[4 * i + 1] = v.y; c0[4 * i + 2] = v.z; c0[4 * i + 3] = v.w;
    }
  }

  float prod1[36];
#pragma unroll
  for (int k = 0; k < 36; ++k) prod1[k] = 0.f;

  // ---- Gaunt stage 1: prod1 = Yw^T((Y c0)^2); also stash f = Y c0 (bf16) ----
  for (int b = 0; b < 12; ++b) {
    float u[11];
#pragma unroll
    for (int i = 0; i < 11; ++i) u[i] = 0.f;
#pragma unroll
    for (int k = 0; k < 36; ++k) u[T.M5[k]] += c0[k] * T.PA[b][k];

    float v[11];
#pragma unroll
    for (int i = 0; i < 11; ++i) v[i] = 0.f;

#pragma unroll
    for (int j = 0; j < 6; ++j) {
      float fpair[2];
#pragma unroll
      for (int h = 0; h < 2; ++h) {
        const int a = 2 * j + h;
        float t = u[5];
#pragma unroll
        for (int m = 1; m <= 5; ++m) {
          t += u[5 + m] * T.CT[a][m];
          t += u[5 - m] * T.ST[a][m];
        }
        fpair[h] = t;
        const float g = t * t;
        v[5] += g;
#pragma unroll
        for (int m = 1; m <= 5; ++m) {
          v[5 + m] += g * T.CT[a][m];
          v[5 - m] += g * T.ST[a][m];
        }
      }
      fsh[b * 6 + j][tid] = bf16rn(fpair[0]) | (bf16rn(fpair[1]) << 16);
    }

#pragma unroll
    for (int k = 0; k < 36; ++k) prod1[k] += v[T.M5[k]] * T.PB[b][k];
  }

  float prod2[36];
#pragma unroll
  for (int k = 0; k < 36; ++k) prod2[k] = 0.f;

  // ---- Gaunt stage 2: prod2 = Yw^T((Y prod1) * f) ----
  for (int b = 0; b < 12; ++b) {
    float u[11];
#pragma unroll
    for (int i = 0; i < 11; ++i) u[i] = 0.f;
#pragma unroll
    for (int k = 0; k < 36; ++k) u[T.M5[k]] += prod1[k] * T.PA[b][k];

    float v[11];
#pragma unroll
    for (int i = 0; i < 11; ++i) v[i] = 0.f;

#pragma unroll
    for (int j = 0; j < 6; ++j) {
      const unsigned pck = fsh[b * 6 + j][tid];
#pragma unroll
      for (int h = 0; h < 2; ++h) {
        const int a = 2 * j + h;
        float t = u[5];
#pragma unroll
        for (int m = 1; m <= 5; ++m) {
          t += u[5 + m] * T.CT[a][m];
          t += u[5 - m] * T.ST[a][m];
        }
        const float f = __uint_as_float(h == 0 ? (pck << 16) : (pck & 0xFFFF0000u));
        const float g = t * f;
        v[5] += g;
#pragma unroll
        for (int m = 1; m <= 5; ++m) {
          v[5 + m] += g * T.CT[a][m];
          v[5 - m] += g * T.ST[a][m];
        }
      }
    }

#pragma unroll
    for (int k = 0; k < 36; ++k) prod2[k] += v[T.M5[k]] * T.PB[b][k];
  }

  // ---- epilogue: wn[nu][l] = sum_e atype[atom][e] * wts[nu][e][ch][l] ----
  float at10[10];
#pragma unroll
  for (int e = 0; e < 10; ++e) at10[e] = atype[(size_t)atom * 10 + e];

  float wn[3][6];
#pragma unroll
  for (int nu = 0; nu < 3; ++nu)
#pragma unroll
    for (int l = 0; l < 6; ++l) wn[nu][l] = 0.f;

#pragma unroll
  for (int nu = 0; nu < 3; ++nu) {
#pragma unroll
    for (int e = 0; e < 10; ++e) {
      const float* wp = wts + ((size_t)(nu * 10 + e) * 128 + tid) * 6;
#pragma unroll
      for (int l = 0; l < 6; ++l) wn[nu][l] += at10[e] * wp[l];
    }
  }

  float* op = out + row * 36;
#pragma unroll
  for (int i = 0; i < 9; ++i) {
    float4 v;
    {
      const int k = 4 * i + 0, l = T.LK[k];
      v.x = wn[0][l] * c0[k] + wn[1][l] * prod1[k] + wn[2][l] * prod2[k];
    }
    {
      const int k = 4 * i + 1, l = T.LK[k];
      v.y = wn[0][l] * c0[k] + wn[1][l] * prod1[k] + wn[2][l] * prod2[k];
    }
    {
      const int k = 4 * i + 2, l = T.LK[k];
      v.z = wn[0][l] * c0[k] + wn[1][l] * prod1[k] + wn[2][l] * prod2[k];
    }
    {
      const int k = 4 * i + 3, l = T.LK[k];
      v.w = wn[0][l] * c0[k] + wn[1][l] * prod1[k] + wn[2][l] * prod2[k];
    }
    reinterpret_cast<float4*>(op)[i] = v;
  }
}

extern "C" void kernel_launch(void* const* d_in, const int* in_sizes, int n_in,
                              void* d_out, int out_size, void* d_ws, size_t ws_size,
                              hipStream_t stream) {
  const float* feat = (const float*)d_in[0];   // [4096,128,36] f32
  const float* atype = (const float*)d_in[1];  // [4096,10] f32
  const float* wts = (const float*)d_in[2];    // [3,10,128,6] f32
  float* out = (float*)d_out;                  // [4096,128,36] f32

  (void)in_sizes; (void)n_in; (void)out_size; (void)d_ws; (void)ws_size;

  // 4096 atoms, one block per atom, 128 channels per block.
  gaunt_s2_kernel<<<4096, 128, 0, stream>>>(feat, atype, wts, out);
}